// Round 1
// baseline (152.993 us; speedup 1.0000x reference)
//
#include <hip/hip_runtime.h>
#include <hip/hip_bf16.h>

// Problem constants (match reference)
constexpr int B   = 64;
constexpr int D   = 8192;
constexpr int NNZ = 1024;
constexpr int DE  = 256;
constexpr int DQK = 256;
constexpr float SCALE = 0.0625f;  // 1/sqrt(256)

// ---------------------------------------------------------------------------
// Kernel P: batch-independent precompute.
//   MT[i*DE + j] = SCALE * sum_o Wq[o,i] * Wk[o,j]   (i = d2, j = d)
//   aux[j]       = m0[j] = SCALE * sum_o Wk[o,j] * bq[o]
//   aux[DE + j]  = g1[j] = SCALE * sum_o Wq[o,j] * bk[o]
//   aux[2*DE]    = g0    = SCALE * sum_o bk[o] * bq[o]
// Grid: DE+1 blocks x DE threads. Block DE computes aux.
// ---------------------------------------------------------------------------
__global__ __launch_bounds__(DE) void precompute_kernel(
    const float* __restrict__ Wq, const float* __restrict__ bq,
    const float* __restrict__ Wk, const float* __restrict__ bk,
    float* __restrict__ MT, float* __restrict__ aux)
{
    const int j = threadIdx.x;
    const int i = blockIdx.x;
    if (i < DE) {
        float acc = 0.f;
        #pragma unroll 8
        for (int o = 0; o < DQK; ++o)
            acc += Wq[o * DE + i] * Wk[o * DE + j];   // Wq: uniform addr (scalar), Wk: coalesced
        MT[i * DE + j] = acc * SCALE;
    } else {
        float a0 = 0.f, a1 = 0.f;
        #pragma unroll 8
        for (int o = 0; o < DQK; ++o) {
            a0 += Wk[o * DE + j] * bq[o];
            a1 += Wq[o * DE + j] * bk[o];
        }
        aux[j]      = a0 * SCALE;
        aux[DE + j] = a1 * SCALE;
        if (j == 0) {
            float g0 = 0.f;
            for (int o = 0; o < DQK; ++o) g0 += bk[o] * bq[o];
            aux[2 * DE] = g0 * SCALE;
        }
    }
}

// ---------------------------------------------------------------------------
// Main kernel: one block (1024 threads = 16 waves) per batch row.
//   Phase 1: zero y row, compact nonzeros of x row into LDS (order-free).
//   Phase 2: w[t] = sum_j val_j * E[(idx_j+1), t]   (4 j-groups x 256 dims)
//   Phase 3: z[t] = sum_d2 MT[d2,t]*w[d2] + s*m0[t];  c = g1.w + s*g0
//   Phase 4: per nonzero j (wave-per-j): fx = E[p_j].z + c;
//            y[b, idx_j] = val_j * (1 + fx)
// ---------------------------------------------------------------------------
__global__ __launch_bounds__(1024) void cattend_main_kernel(
    const float* __restrict__ x, const float* __restrict__ E,
    const float* __restrict__ MT, const float* __restrict__ aux,
    float* __restrict__ y)
{
    const int b   = blockIdx.x;
    const int tid = threadIdx.x;

    __shared__ int   s_idx[NNZ];
    __shared__ float s_val[NNZ];
    __shared__ float s_part[4][DE];
    __shared__ float s_w[DE];
    __shared__ float s_z[DE];
    __shared__ float s_cpart[DE];
    __shared__ int   s_cnt;
    __shared__ float s_s;
    __shared__ float s_c;

    // init LDS (safety: val=0 entries are no-ops in all later math)
    if (tid == 0) s_cnt = 0;
    s_idx[tid] = 0;
    s_val[tid] = 0.f;
    __syncthreads();

    const float* xrow = x + (size_t)b * D;
    float*       yrow = y + (size_t)b * D;

    // ---- Phase 1: zero y row + compact nonzeros ----
    for (int i = tid; i < D / 4; i += 1024) {           // 2 iters
        float4 v4 = reinterpret_cast<const float4*>(xrow)[i];
        reinterpret_cast<float4*>(yrow)[i] = make_float4(0.f, 0.f, 0.f, 0.f);
        float vv[4] = {v4.x, v4.y, v4.z, v4.w};
        #pragma unroll
        for (int u = 0; u < 4; ++u) {
            if (vv[u] != 0.f) {
                int pos = atomicAdd(&s_cnt, 1);
                if (pos < NNZ) {
                    s_idx[pos] = i * 4 + u;
                    s_val[pos] = vv[u];
                }
            }
        }
    }
    __syncthreads();

    // ---- Phase 2: w accumulation (group g of 4 waves handles j = g mod 4) ----
    const int t = tid & (DE - 1);   // dim 0..255
    const int g = tid >> 8;         // group 0..3
    {
        float w = 0.f;
        #pragma unroll 4
        for (int j = g; j < NNZ; j += 4) {
            int   p = s_idx[j] + 1;       // LDS broadcast
            float v = s_val[j];
            w += v * E[(size_t)p * DE + t];  // coalesced 256 floats across group
        }
        s_part[g][t] = w;
    }
    __syncthreads();

    if (tid < DE) {
        s_w[tid] = s_part[0][tid] + s_part[1][tid] + s_part[2][tid] + s_part[3][tid];
    } else if (tid < DE + 64) {
        // wave 4: sum of vals
        int lane = tid - DE;
        float sv = 0.f;
        #pragma unroll
        for (int jj = lane; jj < NNZ; jj += 64) sv += s_val[jj];
        for (int off = 32; off; off >>= 1) sv += __shfl_xor(sv, off);
        if (lane == 0) s_s = sv;
    }
    __syncthreads();

    // ---- Phase 3: z and c ----
    {
        float zp = 0.f;
        #pragma unroll 8
        for (int d2 = (g << 6); d2 < (g << 6) + 64; ++d2)
            zp += s_w[d2] * MT[(size_t)d2 * DE + t];   // coalesced in t
        s_part[g][t] = zp;
    }
    __syncthreads();

    if (tid < DE) {
        float zt = s_part[0][tid] + s_part[1][tid] + s_part[2][tid] + s_part[3][tid]
                 + s_s * aux[tid];                      // + s*m0
        s_z[tid] = zt;
        s_cpart[tid] = aux[DE + tid] * s_w[tid];        // g1[t]*w[t]
    }
    __syncthreads();

    if (tid < 64) {
        float cp = s_cpart[tid] + s_cpart[tid + 64] + s_cpart[tid + 128] + s_cpart[tid + 192];
        for (int off = 32; off; off >>= 1) cp += __shfl_xor(cp, off);
        if (tid == 0) s_c = cp + s_s * aux[2 * DE];
    }
    __syncthreads();

    // ---- Phase 4: scatter. Wave-per-nonzero: fx = E[p].z + c ----
    {
        const int lane = tid & 63;
        const int wv   = tid >> 6;                      // 0..15
        float4 z4 = reinterpret_cast<const float4*>(s_z)[lane];  // z[4*lane .. 4*lane+3]
        for (int j = wv; j < NNZ; j += 16) {
            int p = s_idx[j] + 1;
            float4 e4 = reinterpret_cast<const float4*>(E + (size_t)p * DE)[lane];
            float dot = e4.x * z4.x + e4.y * z4.y + e4.z * z4.z + e4.w * z4.w;
            for (int off = 32; off; off >>= 1) dot += __shfl_xor(dot, off);
            if (lane == 0) {
                float fx = dot + s_c;
                yrow[s_idx[j]] = s_val[j] * (1.f + fx);
            }
        }
    }
}

extern "C" void kernel_launch(void* const* d_in, const int* in_sizes, int n_in,
                              void* d_out, int out_size, void* d_ws, size_t ws_size,
                              hipStream_t stream) {
    // inputs: t, x[B*D], E[(D+1)*DE], Wq[DQK*DE], bq[DQK], Wk[DQK*DE], bk[DQK]
    const float* x  = (const float*)d_in[1];
    const float* E  = (const float*)d_in[2];
    const float* Wq = (const float*)d_in[3];
    const float* bq = (const float*)d_in[4];
    const float* Wk = (const float*)d_in[5];
    const float* bk = (const float*)d_in[6];
    float* y = (float*)d_out;

    float* MT  = (float*)d_ws;            // DE*DE floats = 256 KiB
    float* aux = MT + DE * DE;            // 2*DE+1 floats

    hipLaunchKernelGGL(precompute_kernel, dim3(DE + 1), dim3(DE), 0, stream,
                       Wq, bq, Wk, bk, MT, aux);
    hipLaunchKernelGGL(cattend_main_kernel, dim3(B), dim3(1024), 0, stream,
                       x, E, MT, aux, y);
}

// Round 2
// 108.101 us; speedup vs baseline: 1.4153x; 1.4153x over previous
//
#include <hip/hip_runtime.h>
#include <hip/hip_bf16.h>

// Problem constants (match reference)
constexpr int B   = 64;
constexpr int D   = 8192;
constexpr int NNZ = 1024;
constexpr int DE  = 256;
constexpr int DQK = 256;
constexpr float SCALE = 0.0625f;  // 1/sqrt(256)

constexpr int G     = 16;        // chunks per batch row
constexpr int CHUNK = D / G;     // 512 elements per chunk

// Workspace layout (float offsets)
constexpr size_t OFF_MT    = 0;              // [DE*DE]      = 65536
constexpr size_t OFF_AUX   = 65536;          // m0[256], g1[256], g0  (513)
constexpr size_t OFF_WPART = 66560;          // [B*G*DE]     = 262144
constexpr size_t OFF_SPART = 328704;         // [B*G]        = 1024
constexpr size_t OFF_Z     = 329728;         // [B*DE]       = 16384
constexpr size_t OFF_C     = 346112;         // [B]          = 64
// total 346176 floats = 1.32 MiB

// ---------------------------------------------------------------------------
// K1: MT = SCALE * Wq^T * Wk  (tiled 32x32, 64 blocks) + aux (block 64)
//   MT[i*DE + j] = SCALE * sum_o Wq[o,i] * Wk[o,j]
//   aux[j] = m0[j] = SCALE*sum_o Wk[o,j]*bq[o]
//   aux[DE+j] = g1[j] = SCALE*sum_o Wq[o,j]*bk[o]
//   aux[2*DE] = g0 = SCALE*sum_o bk[o]*bq[o]
// ---------------------------------------------------------------------------
__global__ __launch_bounds__(256) void k1_precompute(
    const float* __restrict__ Wq, const float* __restrict__ bq,
    const float* __restrict__ Wk, const float* __restrict__ bk,
    float* __restrict__ ws)
{
    float* MT  = ws + OFF_MT;
    float* aux = ws + OFF_AUX;
    const int blk = blockIdx.x;
    const int tid = threadIdx.x;

    __shared__ float Aq[32][33];
    __shared__ float Bk[32][33];
    __shared__ float sbq[DQK];
    __shared__ float sbk[DQK];
    __shared__ float rp[256];

    if (blk < 64) {
        const int bi = blk >> 3, bj = blk & 7;
        const int I0 = bi * 32, J0 = bj * 32;
        const int lr = tid >> 5;   // 0..7
        const int lc = tid & 31;   // 0..31
        float acc[4] = {0.f, 0.f, 0.f, 0.f};
        for (int oc = 0; oc < DQK; oc += 32) {
            #pragma unroll
            for (int r = 0; r < 4; ++r) {
                int oo = lr + 8 * r;
                Aq[oo][lc] = Wq[(size_t)(oc + oo) * DE + I0 + lc];
                Bk[oo][lc] = Wk[(size_t)(oc + oo) * DE + J0 + lc];
            }
            __syncthreads();
            #pragma unroll
            for (int oo = 0; oo < 32; ++oo) {
                float bv = Bk[oo][lc];
                #pragma unroll
                for (int r = 0; r < 4; ++r)
                    acc[r] += Aq[oo][lr + 8 * r] * bv;
            }
            __syncthreads();
        }
        #pragma unroll
        for (int r = 0; r < 4; ++r)
            MT[(size_t)(I0 + lr + 8 * r) * DE + (J0 + lc)] = acc[r] * SCALE;
    } else {
        sbq[tid] = bq[tid];
        sbk[tid] = bk[tid];
        __syncthreads();
        float a0 = 0.f, a1 = 0.f;
        #pragma unroll 8
        for (int o = 0; o < DQK; ++o) {
            a0 += Wk[(size_t)o * DE + tid] * sbq[o];
            a1 += Wq[(size_t)o * DE + tid] * sbk[o];
        }
        aux[tid]      = a0 * SCALE;
        aux[DE + tid] = a1 * SCALE;
        // g0 = bq . bk
        rp[tid] = sbq[tid] * sbk[tid];
        __syncthreads();
        if (tid < 128) rp[tid] += rp[tid + 128];
        __syncthreads();
        if (tid < 64) {
            float v = rp[tid] + rp[tid + 64];
            for (int off = 32; off; off >>= 1) v += __shfl_xor(v, off);
            if (tid == 0) aux[2 * DE] = v * SCALE;
        }
    }
}

// ---------------------------------------------------------------------------
// K2: per (b, chunk g): compact local nonzeros, partial w and partial s.
//   wpart[(b*G+g)*DE + t] = sum_{j in chunk} v_j * E[p_j, t]
//   spart[b*G+g]          = sum_{j in chunk} v_j
// Grid: B*G = 1024 blocks x 256 threads.
// ---------------------------------------------------------------------------
__global__ __launch_bounds__(256) void k2_partial(
    const float* __restrict__ x, const float* __restrict__ E,
    float* __restrict__ ws)
{
    const int blk = blockIdx.x;
    const int b = blk >> 4, g = blk & (G - 1);
    const int tid = threadIdx.x;

    __shared__ int   s_idx[CHUNK];
    __shared__ float s_val[CHUNK];
    __shared__ float s_part[4][DE];
    __shared__ int   s_cnt;
    __shared__ float s_sum;

    if (tid == 0) { s_cnt = 0; s_sum = 0.f; }
    __syncthreads();

    const float* xc = x + (size_t)b * D + (size_t)g * CHUNK;
    float2 v2 = reinterpret_cast<const float2*>(xc)[tid];
    float lsum = 0.f;
    if (v2.x != 0.f) { int pos = atomicAdd(&s_cnt, 1); s_idx[pos] = 2 * tid;     s_val[pos] = v2.x; lsum += v2.x; }
    if (v2.y != 0.f) { int pos = atomicAdd(&s_cnt, 1); s_idx[pos] = 2 * tid + 1; s_val[pos] = v2.y; lsum += v2.y; }
    for (int off = 32; off; off >>= 1) lsum += __shfl_xor(lsum, off);
    if ((tid & 63) == 0) atomicAdd(&s_sum, lsum);
    __syncthreads();

    const int cnt  = s_cnt;
    const int lane = tid & 63;
    const int q    = tid >> 6;           // wave id 0..3, handles rows j ≡ q (mod 4)
    const int base = g * CHUNK + 1;      // +1: 1-based embedding ids

    float4 w4 = make_float4(0.f, 0.f, 0.f, 0.f);
    #pragma unroll 2
    for (int j = q; j < cnt; j += 4) {
        int   p = s_idx[j] + base;
        float v = s_val[j];
        float4 e4 = *reinterpret_cast<const float4*>(E + (size_t)p * DE + 4 * lane);
        w4.x += v * e4.x; w4.y += v * e4.y; w4.z += v * e4.z; w4.w += v * e4.w;
    }
    *reinterpret_cast<float4*>(&s_part[q][4 * lane]) = w4;
    __syncthreads();

    float w = s_part[0][tid] + s_part[1][tid] + s_part[2][tid] + s_part[3][tid];
    ws[OFF_WPART + (size_t)blk * DE + tid] = w;
    if (tid == 0) ws[OFF_SPART + blk] = s_sum;
}

// ---------------------------------------------------------------------------
// K3: per batch: combine partials, z = MT^T w + s*m0, c = g1.w + s*g0.
// Grid: B = 64 blocks x 256 threads.
// ---------------------------------------------------------------------------
__global__ __launch_bounds__(256) void k3_combine(float* __restrict__ ws)
{
    const int b   = blockIdx.x;
    const int tid = threadIdx.x;
    const float* MT  = ws + OFF_MT;
    const float* aux = ws + OFF_AUX;

    __shared__ float s_w[DE];
    __shared__ float rp[256];
    __shared__ float s_s;

    float w = 0.f;
    #pragma unroll
    for (int g = 0; g < G; ++g)
        w += ws[OFF_WPART + ((size_t)(b * G + g)) * DE + tid];
    s_w[tid] = w;

    float s = 0.f;
    if (tid < G) s = ws[OFF_SPART + b * G + tid];
    if (tid < 64) {
        for (int off = 8; off; off >>= 1) s += __shfl_xor(s, off);
        if (tid == 0) s_s = s;
    }
    __syncthreads();

    const float sv = s_s;
    float z0 = 0.f, z1 = 0.f, z2 = 0.f, z3 = 0.f;
    for (int d2 = 0; d2 < DE; d2 += 4) {
        z0 += s_w[d2 + 0] * MT[(size_t)(d2 + 0) * DE + tid];
        z1 += s_w[d2 + 1] * MT[(size_t)(d2 + 1) * DE + tid];
        z2 += s_w[d2 + 2] * MT[(size_t)(d2 + 2) * DE + tid];
        z3 += s_w[d2 + 3] * MT[(size_t)(d2 + 3) * DE + tid];
    }
    float z = (z0 + z1) + (z2 + z3) + sv * aux[tid];
    ws[OFF_Z + (size_t)b * DE + tid] = z;

    // c = sum_t g1[t]*w[t] + s*g0
    rp[tid] = aux[DE + tid] * w;
    __syncthreads();
    if (tid < 128) rp[tid] += rp[tid + 128];
    __syncthreads();
    if (tid < 64) {
        float v = rp[tid] + rp[tid + 64];
        for (int off = 32; off; off >>= 1) v += __shfl_xor(v, off);
        if (tid == 0) ws[OFF_C + b] = v + sv * aux[2 * DE];
    }
}

// ---------------------------------------------------------------------------
// K4: per (b, chunk g): zero y chunk, re-derive nonzeros, scatter
//   y[b, idx_j] = v_j * (1 + E[p_j].z[b] + c[b])
// Grid: B*G = 1024 blocks x 256 threads. Wave-per-nonzero dot.
// ---------------------------------------------------------------------------
__global__ __launch_bounds__(256) void k4_scatter(
    const float* __restrict__ x, const float* __restrict__ E,
    const float* __restrict__ ws, float* __restrict__ y)
{
    const int blk = blockIdx.x;
    const int b = blk >> 4, g = blk & (G - 1);
    const int tid = threadIdx.x;

    __shared__ int   s_idx[CHUNK];
    __shared__ float s_val[CHUNK];
    __shared__ float s_z[DE];
    __shared__ int   s_cnt;
    __shared__ float s_c;

    if (tid == 0) { s_cnt = 0; s_c = ws[OFF_C + b]; }
    s_z[tid] = ws[OFF_Z + (size_t)b * DE + tid];
    __syncthreads();

    const float* xc = x + (size_t)b * D + (size_t)g * CHUNK;
    float*       yc = y + (size_t)b * D + (size_t)g * CHUNK;
    float2 v2 = reinterpret_cast<const float2*>(xc)[tid];
    reinterpret_cast<float2*>(yc)[tid] = make_float2(0.f, 0.f);
    if (v2.x != 0.f) { int pos = atomicAdd(&s_cnt, 1); s_idx[pos] = 2 * tid;     s_val[pos] = v2.x; }
    if (v2.y != 0.f) { int pos = atomicAdd(&s_cnt, 1); s_idx[pos] = 2 * tid + 1; s_val[pos] = v2.y; }
    __syncthreads();

    const int cnt  = s_cnt;
    const int lane = tid & 63;
    const int wv   = tid >> 6;
    const int base = g * CHUNK + 1;
    const float c  = s_c;
    float4 z4 = *reinterpret_cast<const float4*>(&s_z[4 * lane]);

    for (int j = wv; j < cnt; j += 4) {
        int p = s_idx[j] + base;
        float4 e4 = *reinterpret_cast<const float4*>(E + (size_t)p * DE + 4 * lane);
        float dot = e4.x * z4.x + e4.y * z4.y + e4.z * z4.z + e4.w * z4.w;
        for (int off = 32; off; off >>= 1) dot += __shfl_xor(dot, off);
        if (lane == 0) yc[s_idx[j]] = s_val[j] * (1.f + dot + c);
    }
}

extern "C" void kernel_launch(void* const* d_in, const int* in_sizes, int n_in,
                              void* d_out, int out_size, void* d_ws, size_t ws_size,
                              hipStream_t stream) {
    // inputs: t, x[B*D], E[(D+1)*DE], Wq[DQK*DE], bq[DQK], Wk[DQK*DE], bk[DQK]
    const float* x  = (const float*)d_in[1];
    const float* E  = (const float*)d_in[2];
    const float* Wq = (const float*)d_in[3];
    const float* bq = (const float*)d_in[4];
    const float* Wk = (const float*)d_in[5];
    const float* bk = (const float*)d_in[6];
    float* y  = (float*)d_out;
    float* ws = (float*)d_ws;

    hipLaunchKernelGGL(k1_precompute, dim3(65),    dim3(256), 0, stream, Wq, bq, Wk, bk, ws);
    hipLaunchKernelGGL(k2_partial,    dim3(B * G), dim3(256), 0, stream, x, E, ws);
    hipLaunchKernelGGL(k3_combine,    dim3(B),     dim3(256), 0, stream, ws);
    hipLaunchKernelGGL(k4_scatter,    dim3(B * G), dim3(256), 0, stream, x, E, ws, y);
}

// Round 3
// 102.331 us; speedup vs baseline: 1.4951x; 1.0564x over previous
//
#include <hip/hip_runtime.h>
#include <hip/hip_bf16.h>

// Problem constants (match reference)
constexpr int B   = 64;
constexpr int D   = 8192;
constexpr int NNZ = 1024;
constexpr int DE  = 256;
constexpr int DQK = 256;
constexpr float SCALE = 0.0625f;  // 1/sqrt(256)

constexpr int G     = 32;        // chunks per batch row
constexpr int CHUNK = D / G;     // 256 elements per chunk
constexpr int NCHUNK = B * G;    // 2048

// Workspace layout (float offsets)
constexpr size_t OFF_MT    = 0;          // [DE*DE] = 65536
constexpr size_t OFF_AUX   = 65536;      // m0[256], g1[256], g0 (513, padded)
constexpr size_t OFF_WPART = 66560;      // [NCHUNK*DE] = 524288
constexpr size_t OFF_SPART = 590848;     // [NCHUNK]
constexpr size_t OFF_Z     = 592896;     // [B*DE] = 16384
constexpr size_t OFF_C     = 609280;     // [B]
constexpr size_t OFF_CCNT  = 609344;     // [NCHUNK] (int)
constexpr size_t OFF_CIDX  = 611392;     // [NCHUNK*CHUNK] (int) = 524288
constexpr size_t OFF_CVAL  = 1135680;    // [NCHUNK*CHUNK] float
// end: 1659968 floats = 6.6 MiB (ws is 256 MiB)

// ---------------------------------------------------------------------------
// Kernel A (fused):
//   blocks 0..63 : MT = SCALE * Wq^T * Wk   (32x32 tiles, LDS-staged)
//   block  64    : aux = {m0, g1, g0}
//   blocks 65+   : per (b, chunk): zero y chunk, compact nonzeros (stash to ws),
//                  partial w and partial s.
// ---------------------------------------------------------------------------
__global__ __launch_bounds__(256) void kA_fused(
    const float* __restrict__ x, const float* __restrict__ E,
    const float* __restrict__ Wq, const float* __restrict__ bq,
    const float* __restrict__ Wk, const float* __restrict__ bk,
    float* __restrict__ ws, float* __restrict__ y)
{
    float* MT  = ws + OFF_MT;
    float* aux = ws + OFF_AUX;
    const int blk = blockIdx.x;
    const int tid = threadIdx.x;

    __shared__ float Aq[32][33];
    __shared__ float Bk[32][33];
    __shared__ float sb0[DQK];
    __shared__ float sb1[DQK];
    __shared__ int   s_idx[CHUNK];
    __shared__ float s_val[CHUNK];
    __shared__ float s_part[4][DE];
    __shared__ int   s_cnt;
    __shared__ float s_sum;

    if (blk < 64) {
        // ---- MT GEMM tile ----
        const int bi = blk >> 3, bj = blk & 7;
        const int I0 = bi * 32, J0 = bj * 32;
        const int lr = tid >> 5;   // 0..7
        const int lc = tid & 31;   // 0..31
        float acc[4] = {0.f, 0.f, 0.f, 0.f};
        for (int oc = 0; oc < DQK; oc += 32) {
            #pragma unroll
            for (int r = 0; r < 4; ++r) {
                int oo = lr + 8 * r;
                Aq[oo][lc] = Wq[(size_t)(oc + oo) * DE + I0 + lc];
                Bk[oo][lc] = Wk[(size_t)(oc + oo) * DE + J0 + lc];
            }
            __syncthreads();
            #pragma unroll
            for (int oo = 0; oo < 32; ++oo) {
                float bv = Bk[oo][lc];
                #pragma unroll
                for (int r = 0; r < 4; ++r)
                    acc[r] += Aq[oo][lr + 8 * r] * bv;
            }
            __syncthreads();
        }
        #pragma unroll
        for (int r = 0; r < 4; ++r)
            MT[(size_t)(I0 + lr + 8 * r) * DE + (J0 + lc)] = acc[r] * SCALE;
    } else if (blk == 64) {
        // ---- aux ----
        sb0[tid] = bq[tid];
        sb1[tid] = bk[tid];
        __syncthreads();
        float a0 = 0.f, a1 = 0.f;
        #pragma unroll 8
        for (int o = 0; o < DQK; ++o) {
            a0 += Wk[(size_t)o * DE + tid] * sb0[o];
            a1 += Wq[(size_t)o * DE + tid] * sb1[o];
        }
        aux[tid]      = a0 * SCALE;
        aux[DE + tid] = a1 * SCALE;
        s_part[0][tid] = sb0[tid] * sb1[tid];
        __syncthreads();
        if (tid < 128) s_part[0][tid] += s_part[0][tid + 128];
        __syncthreads();
        if (tid < 64) {
            float v = s_part[0][tid] + s_part[0][tid + 64];
            for (int off = 32; off; off >>= 1) v += __shfl_xor(v, off);
            if (tid == 0) aux[2 * DE] = v * SCALE;
        }
    } else {
        // ---- partial w / s for one chunk ----
        const int cid = blk - 65;
        const int b = cid >> 5, g = cid & (G - 1);
        if (tid == 0) { s_cnt = 0; s_sum = 0.f; }
        __syncthreads();

        const float* xc = x + (size_t)b * D + (size_t)g * CHUNK;
        float v = xc[tid];
        y[(size_t)b * D + (size_t)g * CHUNK + tid] = 0.f;   // zero y chunk here
        float lsum = v;
        if (v != 0.f) { int pos = atomicAdd(&s_cnt, 1); s_idx[pos] = tid; s_val[pos] = v; }
        for (int off = 32; off; off >>= 1) lsum += __shfl_xor(lsum, off);
        if ((tid & 63) == 0) atomicAdd(&s_sum, lsum);
        __syncthreads();

        const int cnt = s_cnt;
        // stash compacted list for kernel C
        if (tid < cnt) {
            ((int*)(ws + OFF_CIDX))[(size_t)cid * CHUNK + tid] = s_idx[tid];
            (ws + OFF_CVAL)[(size_t)cid * CHUNK + tid] = s_val[tid];
        }
        if (tid == 0) {
            ((int*)(ws + OFF_CCNT))[cid] = cnt;
            ws[OFF_SPART + cid] = s_sum;
        }

        const int lane = tid & 63;
        const int q    = tid >> 6;
        const int base = g * CHUNK + 1;
        float4 w4 = make_float4(0.f, 0.f, 0.f, 0.f);
        #pragma unroll 2
        for (int j = q; j < cnt; j += 4) {
            int   p  = s_idx[j] + base;
            float vv = s_val[j];
            float4 e4 = *reinterpret_cast<const float4*>(E + (size_t)p * DE + 4 * lane);
            w4.x += vv * e4.x; w4.y += vv * e4.y; w4.z += vv * e4.z; w4.w += vv * e4.w;
        }
        *reinterpret_cast<float4*>(&s_part[q][4 * lane]) = w4;
        __syncthreads();

        float w = s_part[0][tid] + s_part[1][tid] + s_part[2][tid] + s_part[3][tid];
        ws[OFF_WPART + (size_t)cid * DE + tid] = w;
    }
}

// ---------------------------------------------------------------------------
// Kernel B: grid 256 = (b, colgroup cg) blocks.
//   reduce w[b] from 32 partials; z[b, cg*64..+63] = MT^T w + s*m0;
//   cg==0 also computes c[b] = g1.w + s*g0
// ---------------------------------------------------------------------------
__global__ __launch_bounds__(256) void kB_combine(float* __restrict__ ws)
{
    const int blk = blockIdx.x;
    const int b = blk >> 2, cg = blk & 3;
    const int tid = threadIdx.x;
    const float* MT  = ws + OFF_MT;
    const float* aux = ws + OFF_AUX;

    __shared__ float s_w[DE];
    __shared__ float s_mp[4][64];
    __shared__ float rp[256];
    __shared__ float s_s;

    float w = 0.f;
    #pragma unroll 8
    for (int g = 0; g < G; ++g)
        w += ws[OFF_WPART + ((size_t)(b * G + g)) * DE + tid];
    s_w[tid] = w;

    if (tid < 32) {
        float sv = ws[OFF_SPART + b * G + tid];
        for (int off = 16; off; off >>= 1) sv += __shfl_xor(sv, off);
        if (tid == 0) s_s = sv;
    }
    __syncthreads();

    const int c = tid & 63, q = tid >> 6;
    const int ocol = cg * 64 + c;
    float acc = 0.f;
    #pragma unroll 8
    for (int d2 = q * 64; d2 < q * 64 + 64; ++d2)
        acc += s_w[d2] * MT[(size_t)d2 * DE + ocol];
    s_mp[q][c] = acc;
    __syncthreads();

    if (tid < 64) {
        float z = s_mp[0][tid] + s_mp[1][tid] + s_mp[2][tid] + s_mp[3][tid]
                + s_s * aux[cg * 64 + tid];
        ws[OFF_Z + (size_t)b * DE + cg * 64 + tid] = z;
    }

    if (cg == 0) {                       // uniform per block — barrier-safe
        rp[tid] = aux[DE + tid] * s_w[tid];
        __syncthreads();
        if (tid < 128) rp[tid] += rp[tid + 128];
        __syncthreads();
        if (tid < 64) {
            float v = rp[tid] + rp[tid + 64];
            for (int off = 32; off; off >>= 1) v += __shfl_xor(v, off);
            if (tid == 0) ws[OFF_C + b] = v + s_s * aux[2 * DE];
        }
    }
}

// ---------------------------------------------------------------------------
// Kernel C: per (b, chunk): load stashed compacted list, wave-per-nonzero
//   fx = E[p].z[b] + c[b];  y[b, idx] = v*(1+fx)
// ---------------------------------------------------------------------------
__global__ __launch_bounds__(256, 8) void kC_scatter(
    const float* __restrict__ E, const float* __restrict__ ws,
    float* __restrict__ y)
{
    const int cid = blockIdx.x;
    const int b = cid >> 5, g = cid & (G - 1);
    const int tid = threadIdx.x;

    __shared__ int   s_idx[CHUNK];
    __shared__ float s_val[CHUNK];
    __shared__ float s_z[DE];
    __shared__ float s_c;
    __shared__ int   s_n;

    s_z[tid] = ws[OFF_Z + (size_t)b * DE + tid];
    if (tid == 0) {
        s_c = ws[OFF_C + b];
        s_n = ((const int*)(ws + OFF_CCNT))[cid];
    }
    __syncthreads();
    const int cnt = s_n;
    if (tid < cnt) {
        s_idx[tid] = ((const int*)(ws + OFF_CIDX))[(size_t)cid * CHUNK + tid];
        s_val[tid] = (ws + OFF_CVAL)[(size_t)cid * CHUNK + tid];
    }
    __syncthreads();

    const int lane = tid & 63;
    const int wv   = tid >> 6;
    const int base = g * CHUNK + 1;
    const float c  = s_c;
    float4 z4 = *reinterpret_cast<const float4*>(&s_z[4 * lane]);
    float* yc = y + (size_t)b * D + (size_t)g * CHUNK;

    #pragma unroll 2
    for (int j = wv; j < cnt; j += 4) {
        int p = s_idx[j] + base;
        float4 e4 = *reinterpret_cast<const float4*>(E + (size_t)p * DE + 4 * lane);
        float dot = e4.x * z4.x + e4.y * z4.y + e4.z * z4.z + e4.w * z4.w;
        for (int off = 32; off; off >>= 1) dot += __shfl_xor(dot, off);
        if (lane == 0) yc[s_idx[j]] = s_val[j] * (1.f + dot + c);
    }
}

extern "C" void kernel_launch(void* const* d_in, const int* in_sizes, int n_in,
                              void* d_out, int out_size, void* d_ws, size_t ws_size,
                              hipStream_t stream) {
    // inputs: t, x[B*D], E[(D+1)*DE], Wq[DQK*DE], bq[DQK], Wk[DQK*DE], bk[DQK]
    const float* x  = (const float*)d_in[1];
    const float* E  = (const float*)d_in[2];
    const float* Wq = (const float*)d_in[3];
    const float* bq = (const float*)d_in[4];
    const float* Wk = (const float*)d_in[5];
    const float* bk = (const float*)d_in[6];
    float* y  = (float*)d_out;
    float* ws = (float*)d_ws;

    hipLaunchKernelGGL(kA_fused,   dim3(65 + NCHUNK), dim3(256), 0, stream,
                       x, E, Wq, bq, Wk, bk, ws, y);
    hipLaunchKernelGGL(kB_combine, dim3(B * 4),       dim3(256), 0, stream, ws);
    hipLaunchKernelGGL(kC_scatter, dim3(NCHUNK),      dim3(256), 0, stream, E, ws, y);
}